// Round 2
// baseline (1268.825 us; speedup 1.0000x reference)
//
#include <hip/hip_runtime.h>

// HierarchicalRouter: B=32768 tokens, H=4096, 16 groups x 16 experts.
// Inputs fp32: hidden[B,H], group_w[16,H], expert_w[16,16,H].
// Output fp32 (concat): [B,256] all_expert_logits, [B] selected_experts, [B] expert_weights.
//
// fp32 end-to-end (argmax fidelity). Kernel 1: group logits + argmax
// (lane=token, 4 waves split H, wave-uniform weight addrs -> s_load).
// Kernel 2: bucketed by (tile, group) so expert weights are workgroup-uniform.

constexpr int Btok = 32768;
constexpr int Hdim = 4096;
constexpr int Gn   = 16;
constexpr int EPGn = 16;
constexpr int En   = 256;
constexpr int Hq   = Hdim / 4;   // per-wave H slice (4 waves per block)
constexpr int TILE = 1024;       // tokens per kernel-2 tile

__global__ __launch_bounds__(256) void k_group(
    const float* __restrict__ hidden, const float* __restrict__ gw,
    unsigned char* __restrict__ gsel)
{
  const int lane = threadIdx.x & 63;
  // readfirstlane: prove wave-uniformity so weight loads become s_load (SGPR).
  const int wq = __builtin_amdgcn_readfirstlane((int)(threadIdx.x >> 6));
  const int token = blockIdx.x * 64 + lane;
  const float* hrow  = hidden + (size_t)token * Hdim + wq * Hq;
  const float* wbase = gw + wq * Hq;

  float acc[Gn];
#pragma unroll
  for (int g = 0; g < Gn; ++g) acc[g] = 0.f;

#pragma unroll 2
  for (int j = 0; j < Hq; j += 4) {
    const float4 h4 = *reinterpret_cast<const float4*>(hrow + j);
#pragma unroll
    for (int g = 0; g < Gn; ++g) {
      const float* wg = wbase + g * Hdim + j;   // uniform addr -> scalar load
      acc[g] += h4.x * wg[0] + h4.y * wg[1] + h4.z * wg[2] + h4.w * wg[3];
    }
  }

  __shared__ float part[4][64][Gn + 1];   // +1 pad: conflict-free reduce
#pragma unroll
  for (int g = 0; g < Gn; ++g) part[wq][lane][g] = acc[g];
  __syncthreads();

  if (wq == 0) {
    float best = -3.4e38f; int bi = 0;
#pragma unroll
    for (int g = 0; g < Gn; ++g) {
      float v = part[0][lane][g] + part[1][lane][g]
              + part[2][lane][g] + part[3][lane][g];
      if (v > best) { best = v; bi = g; }   // first-max tie-break == jnp.argmax
    }
    gsel[token] = (unsigned char)bi;
  }
}

__global__ __launch_bounds__(256) void k_expert(
    const float* __restrict__ hidden, const float* __restrict__ ew,
    const unsigned char* __restrict__ gsel,
    float* __restrict__ out0,   // [B,256]
    float* __restrict__ out1,   // [B] selected expert (as float)
    float* __restrict__ out2)   // [B] expert weight
{
  const int g = blockIdx.x;              // 0..15
  const int tbase = blockIdx.y * TILE;

  __shared__ int   list[TILE];
  __shared__ int   cnt;
  __shared__ float part[4][64][EPGn + 1];
  __shared__ float lrow[64][EPGn + 1];

  if (threadIdx.x == 0) cnt = 0;
  __syncthreads();
  for (int i = threadIdx.x; i < TILE; i += 256) {
    if ((int)gsel[tbase + i] == g) {
      int p = atomicAdd(&cnt, 1);
      list[p] = tbase + i;
    }
  }
  __syncthreads();
  const int n = cnt;

  const int lane = threadIdx.x & 63;
  const int wq = __builtin_amdgcn_readfirstlane((int)(threadIdx.x >> 6));
  const float* wbase = ew + ((size_t)g * EPGn) * Hdim + wq * Hq;

  for (int s0 = 0; s0 < n; s0 += 64) {
    const int ns = min(64, n - s0);
    const int token = list[s0 + ((lane < ns) ? lane : 0)];
    const float* hrow = hidden + (size_t)token * Hdim + wq * Hq;

    float acc[EPGn];
#pragma unroll
    for (int e = 0; e < EPGn; ++e) acc[e] = 0.f;

#pragma unroll 2
    for (int j = 0; j < Hq; j += 4) {
      const float4 h4 = *reinterpret_cast<const float4*>(hrow + j);
#pragma unroll
      for (int e = 0; e < EPGn; ++e) {
        const float* we = wbase + e * Hdim + j;   // uniform -> s_load
        acc[e] += h4.x * we[0] + h4.y * we[1] + h4.z * we[2] + h4.w * we[3];
      }
    }

#pragma unroll
    for (int e = 0; e < EPGn; ++e) part[wq][lane][e] = acc[e];
    __syncthreads();

    if (wq == 0 && lane < ns) {
      float l[EPGn];
      float m = -3.4e38f;
#pragma unroll
      for (int e = 0; e < EPGn; ++e) {
        l[e] = part[0][lane][e] + part[1][lane][e]
             + part[2][lane][e] + part[3][lane][e];
        m = fmaxf(m, l[e]);
      }
      float sum = 0.f;
#pragma unroll
      for (int e = 0; e < EPGn; ++e) sum += expf(l[e] - m);
      int bi = 0; float best = l[0];
#pragma unroll
      for (int e = 1; e < EPGn; ++e) { if (l[e] > best) { best = l[e]; bi = e; } }
      const int tok = list[s0 + lane];
      out1[tok] = (float)(g * EPGn + bi);
      out2[tok] = 1.f / sum;             // exp(max-max)/sum == top prob
#pragma unroll
      for (int e = 0; e < EPGn; ++e) lrow[lane][e] = l[e];
    }
    __syncthreads();

    // Write full 256-wide fp32 row: zeros except the selected group's block.
    const int r = threadIdx.x >> 2;      // 0..63 row in sub-tile
    const int p = threadIdx.x & 3;       // 4 threads per row
    if (r < ns) {
      const int tok = list[s0 + r];
      float* row = out0 + (size_t)tok * En;
#pragma unroll
      for (int i = 0; i < 16; ++i) {
        float4 v;
        if (i == g) {
          v.x = lrow[r][p * 4 + 0];
          v.y = lrow[r][p * 4 + 1];
          v.z = lrow[r][p * 4 + 2];
          v.w = lrow[r][p * 4 + 3];
        } else {
          v.x = 0.f; v.y = 0.f; v.z = 0.f; v.w = 0.f;
        }
        *reinterpret_cast<float4*>(row + i * 16 + p * 4) = v;
      }
    }
    __syncthreads();   // protect part/lrow before next sub-tile
  }
}

extern "C" void kernel_launch(void* const* d_in, const int* in_sizes, int n_in,
                              void* d_out, int out_size, void* d_ws, size_t ws_size,
                              hipStream_t stream) {
  const float* hidden = (const float*)d_in[0];
  const float* gw     = (const float*)d_in[1];
  const float* ew     = (const float*)d_in[2];
  float* out0 = (float*)d_out;
  unsigned char* gsel = (unsigned char*)d_ws;        // 32 KB scratch

  k_group<<<Btok / 64, 256, 0, stream>>>(hidden, gw, gsel);

  float* out1 = out0 + (size_t)Btok * En;
  float* out2 = out1 + Btok;
  k_expert<<<dim3(Gn, Btok / TILE), 256, 0, stream>>>(
      hidden, ew, gsel, out0, out1, out2);
}